// Round 2
// baseline (922.174 us; speedup 1.0000x reference)
//
#include <hip/hip_runtime.h>
#include <stdint.h>
#include <math.h>

#define E_DIM 1024
#define W_DIM 1024

typedef unsigned short u16;

__device__ __forceinline__ float bf2f(u16 u) {
    union { uint32_t i; float f; } v; v.i = ((uint32_t)u) << 16; return v.f;
}
__device__ __forceinline__ u16 f2bf(float f) {
    union { uint32_t i; float f; } v; v.f = f;
    uint32_t lsb = (v.i >> 16) & 1;
    v.i += 0x7fffu + lsb;
    return (u16)(v.i >> 16);
}

// Projection GEMM: C[m,n] = sum_k A[m,k]*B[k,n]; A,B fp32; C bf16 (workspace).
// A: [1024 x 1024] row-major shared across z; B,C: per-z slices.
__global__ __launch_bounds__(256) void gemm_proj(
    const float* __restrict__ A, const float* __restrict__ B,
    u16* __restrict__ C, long strideB, long strideC)
{
    __shared__ float As[16][68];  // [k][m]
    __shared__ float Bs[16][68];  // [k][n]

    const int t  = threadIdx.x;
    const int tx = t & 15, ty = t >> 4;
    const int row0 = blockIdx.y * 64, col0 = blockIdx.x * 64;
    B += (long)blockIdx.z * strideB;
    C += (long)blockIdx.z * strideC;

    const int am = t >> 2, ak = (t & 3) * 4;
    const int bk = t >> 4, bn = (t & 15) * 4;

    float acc[4][4] = {};

    for (int k0 = 0; k0 < E_DIM; k0 += 16) {
        float4 av = *reinterpret_cast<const float4*>(A + (long)(row0 + am) * E_DIM + k0 + ak);
        float4 bv = *reinterpret_cast<const float4*>(B + (long)(k0 + bk) * W_DIM + col0 + bn);
        As[ak + 0][am] = av.x;
        As[ak + 1][am] = av.y;
        As[ak + 2][am] = av.z;
        As[ak + 3][am] = av.w;
        *reinterpret_cast<float4*>(&Bs[bk][bn]) = bv;
        __syncthreads();
        #pragma unroll
        for (int kk = 0; kk < 16; ++kk) {
            float4 a4 = *reinterpret_cast<const float4*>(&As[kk][ty * 4]);
            float4 b4 = *reinterpret_cast<const float4*>(&Bs[kk][tx * 4]);
            float aa[4] = {a4.x, a4.y, a4.z, a4.w};
            float bb[4] = {b4.x, b4.y, b4.z, b4.w};
            #pragma unroll
            for (int i = 0; i < 4; ++i)
                #pragma unroll
                for (int j = 0; j < 4; ++j)
                    acc[i][j] += aa[i] * bb[j];
        }
        __syncthreads();
    }

    #pragma unroll
    for (int i = 0; i < 4; ++i) {
        ushort4 o;
        o.x = f2bf(acc[i][0]);
        o.y = f2bf(acc[i][1]);
        o.z = f2bf(acc[i][2]);
        o.w = f2bf(acc[i][3]);
        *reinterpret_cast<ushort4*>(C + (long)(row0 + ty * 4 + i) * W_DIM + col0 + tx * 4) = o;
    }
}

// Output GEMM: C[m,n] = sum_k A[m,k]*B[k,n] + bias[m]; A fp32, B bf16 (ws), C fp32.
__global__ __launch_bounds__(256) void gemm_out(
    const float* __restrict__ A, const u16* __restrict__ B,
    float* __restrict__ C, const float* __restrict__ bias,
    long strideB, long strideC)
{
    __shared__ float As[16][68];
    __shared__ float Bs[16][68];

    const int t  = threadIdx.x;
    const int tx = t & 15, ty = t >> 4;
    const int row0 = blockIdx.y * 64, col0 = blockIdx.x * 64;
    B += (long)blockIdx.z * strideB;
    C += (long)blockIdx.z * strideC;

    const int am = t >> 2, ak = (t & 3) * 4;
    const int bk = t >> 4, bn = (t & 15) * 4;

    float acc[4][4] = {};

    for (int k0 = 0; k0 < E_DIM; k0 += 16) {
        float4 av = *reinterpret_cast<const float4*>(A + (long)(row0 + am) * E_DIM + k0 + ak);
        ushort4 bv = *reinterpret_cast<const ushort4*>(B + (long)(k0 + bk) * W_DIM + col0 + bn);
        As[ak + 0][am] = av.x;
        As[ak + 1][am] = av.y;
        As[ak + 2][am] = av.z;
        As[ak + 3][am] = av.w;
        *reinterpret_cast<float4*>(&Bs[bk][bn]) =
            make_float4(bf2f(bv.x), bf2f(bv.y), bf2f(bv.z), bf2f(bv.w));
        __syncthreads();
        #pragma unroll
        for (int kk = 0; kk < 16; ++kk) {
            float4 a4 = *reinterpret_cast<const float4*>(&As[kk][ty * 4]);
            float4 b4 = *reinterpret_cast<const float4*>(&Bs[kk][tx * 4]);
            float aa[4] = {a4.x, a4.y, a4.z, a4.w};
            float bb[4] = {b4.x, b4.y, b4.z, b4.w};
            #pragma unroll
            for (int i = 0; i < 4; ++i)
                #pragma unroll
                for (int j = 0; j < 4; ++j)
                    acc[i][j] += aa[i] * bb[j];
        }
        __syncthreads();
    }

    #pragma unroll
    for (int i = 0; i < 4; ++i) {
        float bv = bias ? bias[row0 + ty * 4 + i] : 0.f;
        float4 o = make_float4(acc[i][0] + bv, acc[i][1] + bv, acc[i][2] + bv, acc[i][3] + bv);
        *reinterpret_cast<float4*>(C + (long)(row0 + ty * 4 + i) * W_DIM + col0 + tx * 4) = o;
    }
}

// Flash-style attention with softmax over q (the PV reduction axis).
// Per block: one (b, h, 64-wide k-tile). Online softmax over q-tiles.
// out[d,k] = sum_q V[d,q] * softmax_q(Q[:,q]·K[:,k] masked q<=k) / 32
__global__ __launch_bounds__(256) void attn_k(
    const u16* __restrict__ Kp, const u16* __restrict__ Qp,
    const u16* __restrict__ Vp, u16* __restrict__ Op)
{
    __shared__ float Ks[64][68];   // K tile [d][kl]
    __shared__ float QS[64][68];   // Q tile [d][ql], then reused as S/P [ql][kl]
    __shared__ float Vt[64][68];   // V tile transposed [ql][d]
    __shared__ float alpha_s[64];
    __shared__ float l_s[64];

    const int t = threadIdx.x;
    const int k0 = blockIdx.x * 64;
    const long base = ((long)blockIdx.z * E_DIM + blockIdx.y * 64) * W_DIM;

    const int lr = t >> 2;          // loader row (d)
    const int lc = (t & 3) * 16;    // loader col start

    #pragma unroll
    for (int i = 0; i < 16; i += 4) {
        ushort4 v = *reinterpret_cast<const ushort4*>(Kp + base + (long)lr * W_DIM + k0 + lc + i);
        *reinterpret_cast<float4*>(&Ks[lr][lc + i]) =
            make_float4(bf2f(v.x), bf2f(v.y), bf2f(v.z), bf2f(v.w));
    }

    float m = -INFINITY, l = 0.f;
    float acc[4][4] = {{0.f}};
    const int ql0 = (t & 15) * 4;   // S-compute: rows
    const int kl0 = (t >> 4) * 4;   // S-compute: cols
    const int d0  = (t >> 4) * 4;   // phase-3: rows (d)
    const int klc = (t & 15) * 4;   // phase-3: cols (kl)

    for (int q0 = 0; q0 <= k0; q0 += 64) {
        __syncthreads();  // previous phase-3 reads done; safe to overwrite QS/Vt
        #pragma unroll
        for (int i = 0; i < 16; i += 4) {
            ushort4 qv = *reinterpret_cast<const ushort4*>(Qp + base + (long)lr * W_DIM + q0 + lc + i);
            *reinterpret_cast<float4*>(&QS[lr][lc + i]) =
                make_float4(bf2f(qv.x), bf2f(qv.y), bf2f(qv.z), bf2f(qv.w));
            ushort4 vv = *reinterpret_cast<const ushort4*>(Vp + base + (long)lr * W_DIM + q0 + lc + i);
            Vt[lc + i + 0][lr] = bf2f(vv.x);
            Vt[lc + i + 1][lr] = bf2f(vv.y);
            Vt[lc + i + 2][lr] = bf2f(vv.z);
            Vt[lc + i + 3][lr] = bf2f(vv.w);
        }
        __syncthreads();  // tiles visible (covers Ks on first iter too)

        // S = Q^T K into registers (4x4 per thread)
        float s[4][4] = {{0.f}};
        for (int d = 0; d < 64; ++d) {
            float4 q4 = *reinterpret_cast<const float4*>(&QS[d][ql0]);
            float4 k4 = *reinterpret_cast<const float4*>(&Ks[d][kl0]);
            float qa[4] = {q4.x, q4.y, q4.z, q4.w};
            float ka[4] = {k4.x, k4.y, k4.z, k4.w};
            #pragma unroll
            for (int a = 0; a < 4; ++a)
                #pragma unroll
                for (int b = 0; b < 4; ++b)
                    s[a][b] += qa[a] * ka[b];
        }
        __syncthreads();  // all QS (Q) reads complete, can repurpose as S

        if (q0 == k0) {   // diagonal tile: mask q > k
            #pragma unroll
            for (int a = 0; a < 4; ++a)
                #pragma unroll
                for (int b = 0; b < 4; ++b)
                    if (q0 + ql0 + a > k0 + kl0 + b) s[a][b] = -INFINITY;
        }
        #pragma unroll
        for (int a = 0; a < 4; ++a)
            *reinterpret_cast<float4*>(&QS[ql0 + a][kl0]) =
                make_float4(s[a][0], s[a][1], s[a][2], s[a][3]);
        __syncthreads();  // S visible

        // online softmax per column kl (threads 0..63, one column each)
        if (t < 64) {
            float tmax = -INFINITY;
            #pragma unroll 8
            for (int q = 0; q < 64; ++q) tmax = fmaxf(tmax, QS[q][t]);
            float newm = fmaxf(m, tmax);
            float a = __expf(m - newm);   // first tile: exp(-inf)=0
            float tsum = 0.f;
            #pragma unroll 4
            for (int q = 0; q < 64; ++q) {
                float p = __expf(QS[q][t] - newm);
                QS[q][t] = p;
                tsum += p;
            }
            l = l * a + tsum;
            m = newm;
            alpha_s[t] = a;
        }
        __syncthreads();  // P + alpha visible

        // O = O*alpha + V @ P
        float al[4];
        #pragma unroll
        for (int b = 0; b < 4; ++b) al[b] = alpha_s[klc + b];
        #pragma unroll
        for (int a = 0; a < 4; ++a)
            #pragma unroll
            for (int b = 0; b < 4; ++b)
                acc[a][b] *= al[b];
        for (int q = 0; q < 64; ++q) {
            float4 v4 = *reinterpret_cast<const float4*>(&Vt[q][d0]);
            float4 p4 = *reinterpret_cast<const float4*>(&QS[q][klc]);
            float va[4] = {v4.x, v4.y, v4.z, v4.w};
            float pa[4] = {p4.x, p4.y, p4.z, p4.w};
            #pragma unroll
            for (int a = 0; a < 4; ++a)
                #pragma unroll
                for (int b = 0; b < 4; ++b)
                    acc[a][b] += va[a] * pa[b];
        }
    }

    if (t < 64) l_s[t] = l;
    __syncthreads();

    #pragma unroll
    for (int a = 0; a < 4; ++a) {
        ushort4 o;
        o.x = f2bf(acc[a][0] / l_s[klc + 0] * 0.03125f);
        o.y = f2bf(acc[a][1] / l_s[klc + 1] * 0.03125f);
        o.z = f2bf(acc[a][2] / l_s[klc + 2] * 0.03125f);
        o.w = f2bf(acc[a][3] / l_s[klc + 3] * 0.03125f);
        *reinterpret_cast<ushort4*>(Op + base + (long)(d0 + a) * W_DIM + k0 + klc) = o;
    }
}

extern "C" void kernel_launch(void* const* d_in, const int* in_sizes, int n_in,
                              void* d_out, int out_size, void* d_ws, size_t ws_size,
                              hipStream_t stream)
{
    const float* x  = (const float*)d_in[0];  // [3][B][E][W]; x[0]->K, x[1]->Q, x[2]->V
    const float* LQ = (const float*)d_in[1];
    const float* LK = (const float*)d_in[2];
    const float* LV = (const float*)d_in[3];
    const float* Mw = (const float*)d_in[4];
    const float* bb = (const float*)d_in[5];
    float* out = (float*)d_out;
    u16* ws  = (u16*)d_ws;

    const long EW  = (long)E_DIM * W_DIM;  // 1,048,576
    const long BEW = 4 * EW;               // B=4
    u16* Kp = ws;                          // bf16 intermediates in workspace
    u16* Qp = ws + BEW;
    u16* Vp = ws + 2 * BEW;
    u16* Ao = ws + 3 * BEW;                // total 33.5 MB of ws

    dim3 grid(16, 16, 4), blk(256);
    gemm_proj<<<grid, blk, 0, stream>>>(LK, x,           Kp, EW, EW);
    gemm_proj<<<grid, blk, 0, stream>>>(LQ, x + BEW,     Qp, EW, EW);
    gemm_proj<<<grid, blk, 0, stream>>>(LV, x + 2 * BEW, Vp, EW, EW);
    attn_k<<<grid, blk, 0, stream>>>(Kp, Qp, Vp, Ao);
    gemm_out<<<grid, blk, 0, stream>>>(Mw, Ao, out, bb, EW, EW);
}

// Round 3
// 257.548 us; speedup vs baseline: 3.5806x; 3.5806x over previous
//
#include <hip/hip_runtime.h>
#include <stdint.h>
#include <math.h>

#define E_DIM 1024
#define W_DIM 1024
#define EW 1048576L   // 1024*1024

typedef _Float16 h16;
typedef __attribute__((ext_vector_type(8))) _Float16 h8;
typedef __attribute__((ext_vector_type(4))) float f4;

// ---------------------------------------------------------------------------
// Convert 4 weight matrices fp32 -> fp16, contiguous in ws: [LK|LQ|LV|M]
// ---------------------------------------------------------------------------
__global__ __launch_bounds__(256) void cvt_w(
    const float* __restrict__ a, const float* __restrict__ b,
    const float* __restrict__ c, const float* __restrict__ d,
    h16* __restrict__ out)
{
    const float* srcs[4] = {a, b, c, d};
    const int z = blockIdx.y;
    const int i = blockIdx.x * 256 + threadIdx.x;   // float4 index
    if (i < 262144) {
        float4 v = reinterpret_cast<const float4*>(srcs[z])[i];
        union { h16 h[4]; uint2 u; } o;
        o.h[0] = (h16)v.x; o.h[1] = (h16)v.y; o.h[2] = (h16)v.z; o.h[3] = (h16)v.w;
        reinterpret_cast<uint2*>(out + z * EW)[i] = o.u;
    }
}

// ---------------------------------------------------------------------------
// Transpose-convert x: [12][E][W] fp32 -> [12][W][E] fp16 (64x64 tiles)
// ---------------------------------------------------------------------------
__global__ __launch_bounds__(256) void cvt_t(
    const float* __restrict__ x, h16* __restrict__ xt)
{
    __shared__ float Ts[64][65];   // [w_local][e_local]
    const long sb = blockIdx.z;
    const float* src = x + sb * EW;   // [e][w]
    h16* dst = xt + sb * EW;          // [w][e]
    const int e0 = blockIdx.y * 64, w0 = blockIdx.x * 64;
    const int r = threadIdx.x >> 4, c4 = (threadIdx.x & 15) * 4;

    #pragma unroll
    for (int p = 0; p < 4; ++p) {
        float4 v = *reinterpret_cast<const float4*>(src + (long)(e0 + r + p * 16) * W_DIM + w0 + c4);
        Ts[c4 + 0][r + p * 16] = v.x;
        Ts[c4 + 1][r + p * 16] = v.y;
        Ts[c4 + 2][r + p * 16] = v.z;
        Ts[c4 + 3][r + p * 16] = v.w;
    }
    __syncthreads();
    #pragma unroll
    for (int p = 0; p < 4; ++p) {
        int wr = r + p * 16;
        union { h16 h[4]; uint2 u; } o;
        o.h[0] = (h16)Ts[wr][c4 + 0];
        o.h[1] = (h16)Ts[wr][c4 + 1];
        o.h[2] = (h16)Ts[wr][c4 + 2];
        o.h[3] = (h16)Ts[wr][c4 + 3];
        *reinterpret_cast<uint2*>(dst + (long)(w0 + wr) * E_DIM + e0 + c4) = o.u;
    }
}

// ---------------------------------------------------------------------------
// MFMA GEMM: C[m][n] = sum_k A[m][k] * Bt[n][k]  (all pitches 1024, 1024^3, z=4)
// 128x128 tile / block (4 waves, each 64x64), BK=32, fp32 accum.
// LDS pitch 40 halves (80B): frag ds_read_b128 banks 2-way (free per m136).
// ---------------------------------------------------------------------------
template <int F32OUT>
__global__ __launch_bounds__(256) void gemm_tt(
    const h16* __restrict__ A, long sAz,
    const h16* __restrict__ Bt, long sBz,
    void* __restrict__ C, long sCz,
    const float* __restrict__ bias)
{
    __shared__ h16 As[128 * 40];   // [m][k] pitch 40
    __shared__ h16 Bs[128 * 40];   // [n][k] pitch 40

    const int t = threadIdx.x;
    const int wave = t >> 6, lane = t & 63;
    const int quad = lane >> 4, l16 = lane & 15;
    const int m0 = blockIdx.y * 128, n0 = blockIdx.x * 128;
    const int wm = (wave >> 1) * 64, wn = (wave & 1) * 64;
    A  += blockIdx.z * sAz;
    Bt += blockIdx.z * sBz;

    const int sr = t >> 2;          // staging row 0..63 (and +64)
    const int sg = (t & 3) * 8;     // granule offset in halves (16B)

    f4 acc[4][4] = {};

    uint4 a0 = *reinterpret_cast<const uint4*>(A  + (long)(m0 + sr) * E_DIM + sg);
    uint4 a1 = *reinterpret_cast<const uint4*>(A  + (long)(m0 + sr + 64) * E_DIM + sg);
    uint4 b0 = *reinterpret_cast<const uint4*>(Bt + (long)(n0 + sr) * E_DIM + sg);
    uint4 b1 = *reinterpret_cast<const uint4*>(Bt + (long)(n0 + sr + 64) * E_DIM + sg);

    for (int k0 = 0; k0 < 1024; k0 += 32) {
        __syncthreads();   // previous iter's frag reads complete
        *reinterpret_cast<uint4*>(As + sr * 40 + sg)        = a0;
        *reinterpret_cast<uint4*>(As + (sr + 64) * 40 + sg) = a1;
        *reinterpret_cast<uint4*>(Bs + sr * 40 + sg)        = b0;
        *reinterpret_cast<uint4*>(Bs + (sr + 64) * 40 + sg) = b1;
        __syncthreads();

        if (k0 + 32 < 1024) {   // prefetch next tile while MFMAs run
            a0 = *reinterpret_cast<const uint4*>(A  + (long)(m0 + sr) * E_DIM + k0 + 32 + sg);
            a1 = *reinterpret_cast<const uint4*>(A  + (long)(m0 + sr + 64) * E_DIM + k0 + 32 + sg);
            b0 = *reinterpret_cast<const uint4*>(Bt + (long)(n0 + sr) * E_DIM + k0 + 32 + sg);
            b1 = *reinterpret_cast<const uint4*>(Bt + (long)(n0 + sr + 64) * E_DIM + k0 + 32 + sg);
        }

        h8 av[4], bv[4];
        #pragma unroll
        for (int i = 0; i < 4; ++i) {
            av[i] = *reinterpret_cast<const h8*>(As + (wm + i * 16 + l16) * 40 + quad * 8);
            bv[i] = *reinterpret_cast<const h8*>(Bs + (wn + i * 16 + l16) * 40 + quad * 8);
        }
        #pragma unroll
        for (int mt = 0; mt < 4; ++mt)
            #pragma unroll
            for (int nt = 0; nt < 4; ++nt)
                acc[mt][nt] = __builtin_amdgcn_mfma_f32_16x16x32_f16(av[mt], bv[nt], acc[mt][nt], 0, 0, 0);
    }

    // Epilogue: D row = quad*4+i (within 16-tile), col = l16 (m89-verified layout)
    if (F32OUT) {
        float* Cf = reinterpret_cast<float*>(C) + blockIdx.z * sCz;
        #pragma unroll
        for (int mt = 0; mt < 4; ++mt)
            #pragma unroll
            for (int i = 0; i < 4; ++i) {
                int m = m0 + wm + mt * 16 + quad * 4 + i;
                float bv_ = bias ? bias[m] : 0.f;
                #pragma unroll
                for (int nt = 0; nt < 4; ++nt)
                    Cf[(long)m * W_DIM + n0 + wn + nt * 16 + l16] = acc[mt][nt][i] + bv_;
            }
    } else {
        h16* Ch = reinterpret_cast<h16*>(C) + blockIdx.z * sCz;
        #pragma unroll
        for (int mt = 0; mt < 4; ++mt)
            #pragma unroll
            for (int i = 0; i < 4; ++i) {
                int m = m0 + wm + mt * 16 + quad * 4 + i;
                #pragma unroll
                for (int nt = 0; nt < 4; ++nt)
                    Ch[(long)m * W_DIM + n0 + wn + nt * 16 + l16] = (h16)acc[mt][nt][i];
            }
    }
}

// ---------------------------------------------------------------------------
// MFMA flash attention, softmax over q (the PV reduction axis).
// Block = (b, h, 64-wide k-chunk); wave w owns k-rows [w*16, w*16+16).
// Kt,Qt: [B][W][E] (row = w, col = h*64+d);  V: [B][E][W];  AoT: [B][W][E].
// Online-softmax state lives in registers (C/D row = quad*4+i).
// ---------------------------------------------------------------------------
__global__ __launch_bounds__(256) void attn_mfma(
    const h16* __restrict__ Kt, const h16* __restrict__ Qt,
    const h16* __restrict__ V, h16* __restrict__ AoT)
{
    __shared__ h16 Ks[64 * 72];    // [k_local][d] pitch 72
    __shared__ h16 Qs[64 * 72];    // [q_local][d]
    __shared__ h16 Vs[64 * 72];    // [d][q_local]
    __shared__ h16 Ps[4][16 * 72]; // per-wave P tile [k16][q64]

    const int t = threadIdx.x, wave = t >> 6, lane = t & 63;
    const int quad = lane >> 4, l16 = lane & 15;
    const int b = blockIdx.y >> 4, h = blockIdx.y & 15;
    const int k0 = blockIdx.x * 64;
    const int kw = wave * 16;

    const h16* Ktb = Kt + (long)b * EW + h * 64;
    const h16* Qtb = Qt + (long)b * EW + h * 64;
    const h16* Vb  = V  + (long)b * EW + (long)(h * 64) * W_DIM;

    const int sr = t >> 2;         // staging row 0..63
    const int sg = (t & 3) * 8;    // halves (16B granule)

    *reinterpret_cast<uint4*>(Ks + sr * 72 + sg)      = *reinterpret_cast<const uint4*>(Ktb + (long)(k0 + sr) * E_DIM + sg);
    *reinterpret_cast<uint4*>(Ks + sr * 72 + sg + 32) = *reinterpret_cast<const uint4*>(Ktb + (long)(k0 + sr) * E_DIM + sg + 32);

    float mrow[4], lrow[4];
    #pragma unroll
    for (int i = 0; i < 4; ++i) { mrow[i] = -1e30f; lrow[i] = 0.f; }
    f4 O[4] = {};

    for (int q0 = 0; q0 <= k0; q0 += 64) {
        __syncthreads();   // previous iter's Qs/Vs reads done (covers Ks store on iter 0)
        *reinterpret_cast<uint4*>(Qs + sr * 72 + sg)      = *reinterpret_cast<const uint4*>(Qtb + (long)(q0 + sr) * E_DIM + sg);
        *reinterpret_cast<uint4*>(Qs + sr * 72 + sg + 32) = *reinterpret_cast<const uint4*>(Qtb + (long)(q0 + sr) * E_DIM + sg + 32);
        *reinterpret_cast<uint4*>(Vs + sr * 72 + sg)      = *reinterpret_cast<const uint4*>(Vb + (long)sr * W_DIM + q0 + sg);
        *reinterpret_cast<uint4*>(Vs + sr * 72 + sg + 32) = *reinterpret_cast<const uint4*>(Vb + (long)sr * W_DIM + q0 + sg + 32);
        __syncthreads();

        // S[k][q] = sum_d K[d,k] * Q[d,q]   (A = K^T rows, B = Q^T rows)
        f4 S[4] = {};
        #pragma unroll
        for (int c = 0; c < 2; ++c) {
            h8 av = *reinterpret_cast<const h8*>(Ks + (kw + l16) * 72 + c * 32 + quad * 8);
            #pragma unroll
            for (int nt = 0; nt < 4; ++nt) {
                h8 bv = *reinterpret_cast<const h8*>(Qs + (nt * 16 + l16) * 72 + c * 32 + quad * 8);
                S[nt] = __builtin_amdgcn_mfma_f32_16x16x32_f16(av, bv, S[nt], 0, 0, 0);
            }
        }

        if (q0 == k0) {   // diagonal: mask q > k
            #pragma unroll
            for (int nt = 0; nt < 4; ++nt)
                #pragma unroll
                for (int i = 0; i < 4; ++i)
                    if (q0 + nt * 16 + l16 > k0 + kw + quad * 4 + i) S[nt][i] = -1e30f;
        }

        // online softmax along q; row = quad*4+i, q spread over l16 x 4 tiles
        float al[4];
        #pragma unroll
        for (int i = 0; i < 4; ++i) {
            float mx = fmaxf(fmaxf(S[0][i], S[1][i]), fmaxf(S[2][i], S[3][i]));
            mx = fmaxf(mx, __shfl_xor(mx, 1));
            mx = fmaxf(mx, __shfl_xor(mx, 2));
            mx = fmaxf(mx, __shfl_xor(mx, 4));
            mx = fmaxf(mx, __shfl_xor(mx, 8));
            float nm = fmaxf(mrow[i], mx);
            al[i] = __expf(mrow[i] - nm);
            mrow[i] = nm;
        }
        #pragma unroll
        for (int nt = 0; nt < 4; ++nt)
            #pragma unroll
            for (int i = 0; i < 4; ++i)
                S[nt][i] = __expf(S[nt][i] - mrow[i]);
        #pragma unroll
        for (int i = 0; i < 4; ++i) {
            float sm = S[0][i] + S[1][i] + S[2][i] + S[3][i];
            sm += __shfl_xor(sm, 1);
            sm += __shfl_xor(sm, 2);
            sm += __shfl_xor(sm, 4);
            sm += __shfl_xor(sm, 8);
            lrow[i] = lrow[i] * al[i] + sm;
            #pragma unroll
            for (int dt = 0; dt < 4; ++dt) O[dt][i] *= al[i];
        }

        // P -> per-wave LDS (D-layout -> A-layout round trip)
        #pragma unroll
        for (int nt = 0; nt < 4; ++nt)
            #pragma unroll
            for (int i = 0; i < 4; ++i)
                Ps[wave][(quad * 4 + i) * 72 + nt * 16 + l16] = (h16)S[nt][i];
        asm volatile("" ::: "memory");   // keep ds_read after ds_write (DS is in-order per wave)

        // O[k][d] += sum_q P[k][q] * V[d][q]
        #pragma unroll
        for (int c = 0; c < 2; ++c) {
            h8 pa = *reinterpret_cast<const h8*>(&Ps[wave][l16 * 72 + c * 32 + quad * 8]);
            #pragma unroll
            for (int dt = 0; dt < 4; ++dt) {
                h8 vv = *reinterpret_cast<const h8*>(Vs + (dt * 16 + l16) * 72 + c * 32 + quad * 8);
                O[dt] = __builtin_amdgcn_mfma_f32_16x16x32_f16(pa, vv, O[dt], 0, 0, 0);
            }
        }
    }

    // epilogue: AoT[b][k][h*64+d] = O / l * (1/32)
    #pragma unroll
    for (int dt = 0; dt < 4; ++dt)
        #pragma unroll
        for (int i = 0; i < 4; ++i)
            AoT[(long)b * EW + (long)(k0 + kw + quad * 4 + i) * E_DIM + h * 64 + dt * 16 + l16] =
                (h16)(O[dt][i] / lrow[i] * 0.03125f);
}

// ---------------------------------------------------------------------------
extern "C" void kernel_launch(void* const* d_in, const int* in_sizes, int n_in,
                              void* d_out, int out_size, void* d_ws, size_t ws_size,
                              hipStream_t stream)
{
    const float* x  = (const float*)d_in[0];  // [3][B][E][W]; x[0]->K, x[1]->Q, x[2]->V
    const float* LQ = (const float*)d_in[1];
    const float* LK = (const float*)d_in[2];
    const float* LV = (const float*)d_in[3];
    const float* Mw = (const float*)d_in[4];
    const float* bb = (const float*)d_in[5];
    float* out = (float*)d_out;
    h16* ws = (h16*)d_ws;

    // ws layout (halves), 64 MiB total
    h16* xh  = ws;                    // [12][W][E] transposed x
    h16* LKh = ws + 12 * EW;
    h16* LQh = ws + 13 * EW;
    h16* LVh = ws + 14 * EW;
    h16* Mh  = ws + 15 * EW;
    h16* Kp  = ws + 16 * EW;          // [B][W][E]  (K^T)
    h16* Qp  = ws + 20 * EW;          // [B][W][E]  (Q^T)
    h16* Vp  = ws + 24 * EW;          // [B][E][W]  (V)
    h16* Ao  = ws + 28 * EW;          // [B][W][E]  (out^T)

    cvt_w<<<dim3(1024, 4), 256, 0, stream>>>(LK, LQ, LV, Mw, LKh);
    cvt_t<<<dim3(16, 16, 12), 256, 0, stream>>>(x, xh);

    dim3 gg(8, 8, 4), blk(256);
    // K^T[w][e] = sum_k x0^T[w][k] * LK[e][k]
    gemm_tt<0><<<gg, blk, 0, stream>>>(xh,          EW, LKh, 0,  Kp, EW, nullptr);
    // Q^T[w][e] = sum_k x1^T[w][k] * LQ[e][k]
    gemm_tt<0><<<gg, blk, 0, stream>>>(xh + 4 * EW, EW, LQh, 0,  Qp, EW, nullptr);
    // V[e][w]   = sum_k LV[e][k] * x2^T[w][k]
    gemm_tt<0><<<gg, blk, 0, stream>>>(LVh, 0, xh + 8 * EW, EW,  Vp, EW, nullptr);

    attn_mfma<<<dim3(16, 64), blk, 0, stream>>>(Kp, Qp, Vp, Ao);

    // out[o][w] = sum_e M[o][e] * Ao^T[w][e] + b[o]
    gemm_tt<1><<<gg, blk, 0, stream>>>(Mh, 0, Ao, EW, out, EW, bb);
}

// Round 4
// 226.825 us; speedup vs baseline: 4.0656x; 1.1354x over previous
//
#include <hip/hip_runtime.h>
#include <stdint.h>
#include <math.h>

#define E_DIM 1024
#define W_DIM 1024
#define EW 1048576L   // 1024*1024

typedef _Float16 h16;
typedef __attribute__((ext_vector_type(8))) _Float16 h8;
typedef __attribute__((ext_vector_type(4))) float f4;

__device__ __forceinline__ void async_copy16(h16* lds, const h16* g) {
    __builtin_amdgcn_global_load_lds(
        (const __attribute__((address_space(1))) void*)g,
        (__attribute__((address_space(3))) void*)lds, 16, 0, 0);
}

// ---------------------------------------------------------------------------
// Convert 4 weight matrices fp32 -> fp16, contiguous in ws: [LK|LQ|LV|M]
// ---------------------------------------------------------------------------
__global__ __launch_bounds__(256) void cvt_w(
    const float* __restrict__ a, const float* __restrict__ b,
    const float* __restrict__ c, const float* __restrict__ d,
    h16* __restrict__ out)
{
    const float* srcs[4] = {a, b, c, d};
    const int z = blockIdx.y;
    const int i = blockIdx.x * 256 + threadIdx.x;   // float4 index
    if (i < 262144) {
        float4 v = reinterpret_cast<const float4*>(srcs[z])[i];
        union { h16 h[4]; uint2 u; } o;
        o.h[0] = (h16)v.x; o.h[1] = (h16)v.y; o.h[2] = (h16)v.z; o.h[3] = (h16)v.w;
        reinterpret_cast<uint2*>(out + z * EW)[i] = o.u;
    }
}

// ---------------------------------------------------------------------------
// Transpose-convert x: [12][E][W] fp32 -> [12][W][E] fp16 (64x64 tiles)
// ---------------------------------------------------------------------------
__global__ __launch_bounds__(256) void cvt_t(
    const float* __restrict__ x, h16* __restrict__ xt)
{
    __shared__ float Ts[64][65];   // [w_local][e_local]
    const long sb = blockIdx.z;
    const float* src = x + sb * EW;   // [e][w]
    h16* dst = xt + sb * EW;          // [w][e]
    const int e0 = blockIdx.y * 64, w0 = blockIdx.x * 64;
    const int r = threadIdx.x >> 4, c4 = (threadIdx.x & 15) * 4;

    #pragma unroll
    for (int p = 0; p < 4; ++p) {
        float4 v = *reinterpret_cast<const float4*>(src + (long)(e0 + r + p * 16) * W_DIM + w0 + c4);
        Ts[c4 + 0][r + p * 16] = v.x;
        Ts[c4 + 1][r + p * 16] = v.y;
        Ts[c4 + 2][r + p * 16] = v.z;
        Ts[c4 + 3][r + p * 16] = v.w;
    }
    __syncthreads();
    #pragma unroll
    for (int p = 0; p < 4; ++p) {
        int wr = r + p * 16;
        union { h16 h[4]; uint2 u; } o;
        o.h[0] = (h16)Ts[wr][c4 + 0];
        o.h[1] = (h16)Ts[wr][c4 + 1];
        o.h[2] = (h16)Ts[wr][c4 + 2];
        o.h[3] = (h16)Ts[wr][c4 + 3];
        *reinterpret_cast<uint2*>(dst + (long)(w0 + wr) * E_DIM + e0 + c4) = o.u;
    }
}

// ---------------------------------------------------------------------------
// Fused projection GEMMs (K, Q, V) in one dispatch: z = proj*4 + batch.
// C[m][n] = sum_k A[m][k] * Bt[n][k]; 128x128 tile, BK=32, m97-style
// global_load_lds staging (pitch 32 halves = 64B rows, per-wave contiguous).
// ---------------------------------------------------------------------------
__global__ __launch_bounds__(256) void gemm_proj3(
    const h16* __restrict__ xh, const h16* __restrict__ Wts,
    h16* __restrict__ KQV)
{
    __shared__ h16 As[128 * 32];   // [m][k] pitch 32 (no pad: needed by lds-DMA)
    __shared__ h16 Bs[128 * 32];   // [n][k] pitch 32

    const int t = threadIdx.x;
    const int wave = t >> 6, lane = t & 63;
    const int quad = lane >> 4, l16 = lane & 15;
    const int m0 = blockIdx.y * 128, n0 = blockIdx.x * 128;
    const int wm = (wave >> 1) * 64, wn = (wave & 1) * 64;

    const int proj = blockIdx.z >> 2, bz = blockIdx.z & 3;
    const h16 *A, *Bt; h16* C;
    if (proj == 0)      { A = xh + bz * EW;       Bt = Wts;          C = KQV + bz * EW; }
    else if (proj == 1) { A = xh + (4 + bz) * EW; Bt = Wts + EW;     C = KQV + (4 + bz) * EW; }
    else                { A = Wts + 2 * EW;       Bt = xh + (8 + bz) * EW; C = KQV + (8 + bz) * EW; }

    const int sr = t >> 2;          // staging row 0..63 (and +64)
    const int sg = (t & 3) * 8;     // granule offset in halves (16B)

    f4 acc[4][4] = {};

    for (int k0 = 0; k0 < 1024; k0 += 32) {
        __syncthreads();   // previous iter's frag reads complete
        async_copy16(As + sr * 32 + sg,        A  + (long)(m0 + sr) * E_DIM + k0 + sg);
        async_copy16(As + (sr + 64) * 32 + sg, A  + (long)(m0 + sr + 64) * E_DIM + k0 + sg);
        async_copy16(Bs + sr * 32 + sg,        Bt + (long)(n0 + sr) * E_DIM + k0 + sg);
        async_copy16(Bs + (sr + 64) * 32 + sg, Bt + (long)(n0 + sr + 64) * E_DIM + k0 + sg);
        __syncthreads();   // vmcnt drained by barrier semantics

        h8 av[4], bv[4];
        #pragma unroll
        for (int i = 0; i < 4; ++i) {
            av[i] = *reinterpret_cast<const h8*>(As + (wm + i * 16 + l16) * 32 + quad * 8);
            bv[i] = *reinterpret_cast<const h8*>(Bs + (wn + i * 16 + l16) * 32 + quad * 8);
        }
        #pragma unroll
        for (int mt = 0; mt < 4; ++mt)
            #pragma unroll
            for (int nt = 0; nt < 4; ++nt)
                acc[mt][nt] = __builtin_amdgcn_mfma_f32_16x16x32_f16(av[mt], bv[nt], acc[mt][nt], 0, 0, 0);
    }

    // D row = quad*4+i within 16-tile, col = l16 (m89-verified)
    #pragma unroll
    for (int mt = 0; mt < 4; ++mt)
        #pragma unroll
        for (int i = 0; i < 4; ++i) {
            int m = m0 + wm + mt * 16 + quad * 4 + i;
            #pragma unroll
            for (int nt = 0; nt < 4; ++nt)
                C[(long)m * W_DIM + n0 + wn + nt * 16 + l16] = (h16)acc[mt][nt][i];
        }
}

// ---------------------------------------------------------------------------
// Output GEMM: out[m][n] = sum_k M[m][k] * AoT[n][k] + bias[m]; fp32 out.
// Register-prefetch staging (1 block/CU here; prefetch beats the lds-DMA
// barrier drain when no co-resident block covers it). LDS pitch 40.
// ---------------------------------------------------------------------------
__global__ __launch_bounds__(256) void gemm_out(
    const h16* __restrict__ A, const h16* __restrict__ Bt, long sBz,
    float* __restrict__ C, long sCz, const float* __restrict__ bias)
{
    __shared__ h16 As[128 * 40];
    __shared__ h16 Bs[128 * 40];

    const int t = threadIdx.x;
    const int wave = t >> 6, lane = t & 63;
    const int quad = lane >> 4, l16 = lane & 15;
    const int m0 = blockIdx.y * 128, n0 = blockIdx.x * 128;
    const int wm = (wave >> 1) * 64, wn = (wave & 1) * 64;
    Bt += blockIdx.z * sBz;

    const int sr = t >> 2;
    const int sg = (t & 3) * 8;

    f4 acc[4][4] = {};

    uint4 a0 = *reinterpret_cast<const uint4*>(A  + (long)(m0 + sr) * E_DIM + sg);
    uint4 a1 = *reinterpret_cast<const uint4*>(A  + (long)(m0 + sr + 64) * E_DIM + sg);
    uint4 b0 = *reinterpret_cast<const uint4*>(Bt + (long)(n0 + sr) * E_DIM + sg);
    uint4 b1 = *reinterpret_cast<const uint4*>(Bt + (long)(n0 + sr + 64) * E_DIM + sg);

    for (int k0 = 0; k0 < 1024; k0 += 32) {
        __syncthreads();
        *reinterpret_cast<uint4*>(As + sr * 40 + sg)        = a0;
        *reinterpret_cast<uint4*>(As + (sr + 64) * 40 + sg) = a1;
        *reinterpret_cast<uint4*>(Bs + sr * 40 + sg)        = b0;
        *reinterpret_cast<uint4*>(Bs + (sr + 64) * 40 + sg) = b1;
        __syncthreads();

        if (k0 + 32 < 1024) {
            a0 = *reinterpret_cast<const uint4*>(A  + (long)(m0 + sr) * E_DIM + k0 + 32 + sg);
            a1 = *reinterpret_cast<const uint4*>(A  + (long)(m0 + sr + 64) * E_DIM + k0 + 32 + sg);
            b0 = *reinterpret_cast<const uint4*>(Bt + (long)(n0 + sr) * E_DIM + k0 + 32 + sg);
            b1 = *reinterpret_cast<const uint4*>(Bt + (long)(n0 + sr + 64) * E_DIM + k0 + 32 + sg);
        }

        h8 av[4], bv[4];
        #pragma unroll
        for (int i = 0; i < 4; ++i) {
            av[i] = *reinterpret_cast<const h8*>(As + (wm + i * 16 + l16) * 40 + quad * 8);
            bv[i] = *reinterpret_cast<const h8*>(Bs + (wn + i * 16 + l16) * 40 + quad * 8);
        }
        #pragma unroll
        for (int mt = 0; mt < 4; ++mt)
            #pragma unroll
            for (int nt = 0; nt < 4; ++nt)
                acc[mt][nt] = __builtin_amdgcn_mfma_f32_16x16x32_f16(av[mt], bv[nt], acc[mt][nt], 0, 0, 0);
    }

    float* Cf = C + blockIdx.z * sCz;
    #pragma unroll
    for (int mt = 0; mt < 4; ++mt)
        #pragma unroll
        for (int i = 0; i < 4; ++i) {
            int m = m0 + wm + mt * 16 + quad * 4 + i;
            float bv_ = bias ? bias[m] : 0.f;
            #pragma unroll
            for (int nt = 0; nt < 4; ++nt)
                Cf[(long)m * W_DIM + n0 + wn + nt * 16 + l16] = acc[mt][nt][i] + bv_;
        }
}

// ---------------------------------------------------------------------------
// MFMA flash attention, softmax over q (the PV reduction axis).
// Block = (b, h, 64-wide k-chunk); wave w owns k-rows [w*16, w*16+16).
// Register-prefetch of next q-tile's Q/V overlaps compute with global loads.
// ---------------------------------------------------------------------------
__global__ __launch_bounds__(256) void attn_mfma(
    const h16* __restrict__ Kt, const h16* __restrict__ Qt,
    const h16* __restrict__ V, h16* __restrict__ AoT)
{
    __shared__ h16 Ks[64 * 72];    // [k_local][d] pitch 72
    __shared__ h16 Qs[64 * 72];    // [q_local][d]
    __shared__ h16 Vs[64 * 72];    // [d][q_local]
    __shared__ h16 Ps[4][16 * 72]; // per-wave P tile [k16][q64]

    const int t = threadIdx.x, wave = t >> 6, lane = t & 63;
    const int quad = lane >> 4, l16 = lane & 15;
    const int b = blockIdx.y >> 4, h = blockIdx.y & 15;
    const int k0 = blockIdx.x * 64;
    const int kw = wave * 16;

    const h16* Ktb = Kt + (long)b * EW + h * 64;
    const h16* Qtb = Qt + (long)b * EW + h * 64;
    const h16* Vb  = V  + (long)b * EW + (long)(h * 64) * W_DIM;

    const int sr = t >> 2;         // staging row 0..63
    const int sg = (t & 3) * 8;    // halves (16B granule)

    uint4 ka = *reinterpret_cast<const uint4*>(Ktb + (long)(k0 + sr) * E_DIM + sg);
    uint4 kb = *reinterpret_cast<const uint4*>(Ktb + (long)(k0 + sr) * E_DIM + sg + 32);
    uint4 qa = *reinterpret_cast<const uint4*>(Qtb + (long)sr * E_DIM + sg);
    uint4 qb = *reinterpret_cast<const uint4*>(Qtb + (long)sr * E_DIM + sg + 32);
    uint4 va = *reinterpret_cast<const uint4*>(Vb + (long)sr * W_DIM + sg);
    uint4 vb = *reinterpret_cast<const uint4*>(Vb + (long)sr * W_DIM + sg + 32);

    float mrow[4], lrow[4];
    #pragma unroll
    for (int i = 0; i < 4; ++i) { mrow[i] = -1e30f; lrow[i] = 0.f; }
    f4 O[4] = {};

    for (int q0 = 0; q0 <= k0; q0 += 64) {
        __syncthreads();   // previous iter's Qs/Vs reads done
        if (q0 == 0) {
            *reinterpret_cast<uint4*>(Ks + sr * 72 + sg)      = ka;
            *reinterpret_cast<uint4*>(Ks + sr * 72 + sg + 32) = kb;
        }
        *reinterpret_cast<uint4*>(Qs + sr * 72 + sg)      = qa;
        *reinterpret_cast<uint4*>(Qs + sr * 72 + sg + 32) = qb;
        *reinterpret_cast<uint4*>(Vs + sr * 72 + sg)      = va;
        *reinterpret_cast<uint4*>(Vs + sr * 72 + sg + 32) = vb;
        __syncthreads();

        if (q0 + 64 <= k0) {   // prefetch next q-tile while computing this one
            qa = *reinterpret_cast<const uint4*>(Qtb + (long)(q0 + 64 + sr) * E_DIM + sg);
            qb = *reinterpret_cast<const uint4*>(Qtb + (long)(q0 + 64 + sr) * E_DIM + sg + 32);
            va = *reinterpret_cast<const uint4*>(Vb + (long)sr * W_DIM + q0 + 64 + sg);
            vb = *reinterpret_cast<const uint4*>(Vb + (long)sr * W_DIM + q0 + 64 + sg + 32);
        }

        // S[k][q] = sum_d K[d,k] * Q[d,q]
        f4 S[4] = {};
        #pragma unroll
        for (int c = 0; c < 2; ++c) {
            h8 av = *reinterpret_cast<const h8*>(Ks + (kw + l16) * 72 + c * 32 + quad * 8);
            #pragma unroll
            for (int nt = 0; nt < 4; ++nt) {
                h8 bv = *reinterpret_cast<const h8*>(Qs + (nt * 16 + l16) * 72 + c * 32 + quad * 8);
                S[nt] = __builtin_amdgcn_mfma_f32_16x16x32_f16(av, bv, S[nt], 0, 0, 0);
            }
        }

        if (q0 == k0) {   // diagonal: mask q > k
            #pragma unroll
            for (int nt = 0; nt < 4; ++nt)
                #pragma unroll
                for (int i = 0; i < 4; ++i)
                    if (q0 + nt * 16 + l16 > k0 + kw + quad * 4 + i) S[nt][i] = -1e30f;
        }

        // online softmax along q; row = quad*4+i, q spread over l16 x 4 tiles
        float al[4];
        #pragma unroll
        for (int i = 0; i < 4; ++i) {
            float mx = fmaxf(fmaxf(S[0][i], S[1][i]), fmaxf(S[2][i], S[3][i]));
            mx = fmaxf(mx, __shfl_xor(mx, 1));
            mx = fmaxf(mx, __shfl_xor(mx, 2));
            mx = fmaxf(mx, __shfl_xor(mx, 4));
            mx = fmaxf(mx, __shfl_xor(mx, 8));
            float nm = fmaxf(mrow[i], mx);
            al[i] = __expf(mrow[i] - nm);
            mrow[i] = nm;
        }
        #pragma unroll
        for (int nt = 0; nt < 4; ++nt)
            #pragma unroll
            for (int i = 0; i < 4; ++i)
                S[nt][i] = __expf(S[nt][i] - mrow[i]);
        #pragma unroll
        for (int i = 0; i < 4; ++i) {
            float sm = S[0][i] + S[1][i] + S[2][i] + S[3][i];
            sm += __shfl_xor(sm, 1);
            sm += __shfl_xor(sm, 2);
            sm += __shfl_xor(sm, 4);
            sm += __shfl_xor(sm, 8);
            lrow[i] = lrow[i] * al[i] + sm;
            #pragma unroll
            for (int dt = 0; dt < 4; ++dt) O[dt][i] *= al[i];
        }

        // P -> per-wave LDS (D-layout -> A-layout round trip)
        #pragma unroll
        for (int nt = 0; nt < 4; ++nt)
            #pragma unroll
            for (int i = 0; i < 4; ++i)
                Ps[wave][(quad * 4 + i) * 72 + nt * 16 + l16] = (h16)S[nt][i];
        asm volatile("" ::: "memory");   // DS in-order per wave; keep read after write

        // O[k][d] += sum_q P[k][q] * V[d][q]
        #pragma unroll
        for (int c = 0; c < 2; ++c) {
            h8 pa = *reinterpret_cast<const h8*>(&Ps[wave][l16 * 72 + c * 32 + quad * 8]);
            #pragma unroll
            for (int dt = 0; dt < 4; ++dt) {
                h8 vv = *reinterpret_cast<const h8*>(Vs + (dt * 16 + l16) * 72 + c * 32 + quad * 8);
                O[dt] = __builtin_amdgcn_mfma_f32_16x16x32_f16(pa, vv, O[dt], 0, 0, 0);
            }
        }
    }

    // epilogue: AoT[b][k][h*64+d] = O / l * (1/32)
    #pragma unroll
    for (int dt = 0; dt < 4; ++dt)
        #pragma unroll
        for (int i = 0; i < 4; ++i)
            AoT[(long)b * EW + (long)(k0 + kw + quad * 4 + i) * E_DIM + h * 64 + dt * 16 + l16] =
                (h16)(O[dt][i] / lrow[i] * 0.03125f);
}

// ---------------------------------------------------------------------------
extern "C" void kernel_launch(void* const* d_in, const int* in_sizes, int n_in,
                              void* d_out, int out_size, void* d_ws, size_t ws_size,
                              hipStream_t stream)
{
    const float* x  = (const float*)d_in[0];  // [3][B][E][W]; x[0]->K, x[1]->Q, x[2]->V
    const float* LQ = (const float*)d_in[1];
    const float* LK = (const float*)d_in[2];
    const float* LV = (const float*)d_in[3];
    const float* Mw = (const float*)d_in[4];
    const float* bb = (const float*)d_in[5];
    float* out = (float*)d_out;
    h16* ws = (h16*)d_ws;

    // ws layout (halves), 64 MiB total
    h16* xh  = ws;                    // [12][W][E] transposed x
    h16* LKh = ws + 12 * EW;          // weights contiguous: [LK|LQ|LV|M]
    h16* Mh  = ws + 15 * EW;
    h16* Kp  = ws + 16 * EW;          // [B][W][E] (K^T); Qp at +4EW; Vp [B][E][W] at +8EW
    h16* Qp  = ws + 20 * EW;
    h16* Vp  = ws + 24 * EW;
    h16* Ao  = ws + 28 * EW;          // [B][W][E]  (out^T)

    cvt_w<<<dim3(1024, 4), 256, 0, stream>>>(LK, LQ, LV, Mw, LKh);
    cvt_t<<<dim3(16, 16, 12), 256, 0, stream>>>(x, xh);

    dim3 blk(256);
    // K^T = x0^T·LK^T, Q^T = x1^T·LQ^T, V = LV·x2 — one fused dispatch (768 blocks)
    gemm_proj3<<<dim3(8, 8, 12), blk, 0, stream>>>(xh, LKh, Kp);

    attn_mfma<<<dim3(16, 64), blk, 0, stream>>>(Kp, Qp, Vp, Ao);

    // out[o][w] = sum_e M[o][e] * Ao^T[w][e] + b[o]
    gemm_out<<<dim3(8, 8, 4), blk, 0, stream>>>(Mh, Ao, EW, out, EW, bb);
}

// Round 5
// 222.601 us; speedup vs baseline: 4.1427x; 1.0190x over previous
//
#include <hip/hip_runtime.h>
#include <stdint.h>
#include <math.h>

#define E_DIM 1024
#define W_DIM 1024
#define EW 1048576L   // 1024*1024

typedef _Float16 h16;
typedef __attribute__((ext_vector_type(8))) _Float16 h8;
typedef __attribute__((ext_vector_type(4))) float f4;

__device__ __forceinline__ void async_copy16(h16* lds, const h16* g) {
    __builtin_amdgcn_global_load_lds(
        (const __attribute__((address_space(1))) void*)g,
        (__attribute__((address_space(3))) void*)lds, 16, 0, 0);
}

// ---------------------------------------------------------------------------
// prep: z<12 -> transpose-convert x [12][E][W] fp32 -> [12][W][E] fp16;
//       z>=12 -> convert weight (z-12) fp32 -> fp16 into wh[LK|LQ|LV|M].
// ---------------------------------------------------------------------------
__global__ __launch_bounds__(256) void prep(
    const float* __restrict__ x, const float* __restrict__ LK,
    const float* __restrict__ LQ, const float* __restrict__ LV,
    const float* __restrict__ Mw, h16* __restrict__ xt, h16* __restrict__ wh)
{
    __shared__ float Ts[64][65];
    const int z = blockIdx.z;
    const int t = threadIdx.x;
    if (z < 12) {
        const float* src = x + (long)z * EW;   // [e][w]
        h16* dst = xt + (long)z * EW;          // [w][e]
        const int e0 = blockIdx.y * 64, w0 = blockIdx.x * 64;
        const int r = t >> 4, c4 = (t & 15) * 4;
        #pragma unroll
        for (int p = 0; p < 4; ++p) {
            float4 v = *reinterpret_cast<const float4*>(src + (long)(e0 + r + p * 16) * W_DIM + w0 + c4);
            Ts[c4 + 0][r + p * 16] = v.x;
            Ts[c4 + 1][r + p * 16] = v.y;
            Ts[c4 + 2][r + p * 16] = v.z;
            Ts[c4 + 3][r + p * 16] = v.w;
        }
        __syncthreads();
        #pragma unroll
        for (int p = 0; p < 4; ++p) {
            int wr = r + p * 16;
            union { h16 h[4]; uint2 u; } o;
            o.h[0] = (h16)Ts[wr][c4 + 0];
            o.h[1] = (h16)Ts[wr][c4 + 1];
            o.h[2] = (h16)Ts[wr][c4 + 2];
            o.h[3] = (h16)Ts[wr][c4 + 3];
            *reinterpret_cast<uint2*>(dst + (long)(w0 + wr) * E_DIM + e0 + c4) = o.u;
        }
    } else {
        const float* srcs[4] = {LK, LQ, LV, Mw};
        const float* s = srcs[z - 12];
        h16* o = wh + (long)(z - 12) * EW;
        long base = ((long)(blockIdx.y * 16 + blockIdx.x)) * 1024 + t;  // float4 idx
        #pragma unroll
        for (int k = 0; k < 4; ++k) {
            long i = base + k * 256;
            float4 v = reinterpret_cast<const float4*>(s)[i];
            union { h16 h[4]; uint2 u; } u;
            u.h[0] = (h16)v.x; u.h[1] = (h16)v.y; u.h[2] = (h16)v.z; u.h[3] = (h16)v.w;
            reinterpret_cast<uint2*>(o)[i] = u.u;
        }
    }
}

// ---------------------------------------------------------------------------
// Fused projection GEMMs (K, Q, V), z = proj*4 + batch. 128x128, BK=32,
// global_load_lds staging (pitch 32 halves, lane*16-contiguous). Unchanged.
// ---------------------------------------------------------------------------
__global__ __launch_bounds__(256) void gemm_proj3(
    const h16* __restrict__ xh, const h16* __restrict__ Wts,
    h16* __restrict__ KQV)
{
    __shared__ h16 As[128 * 32];
    __shared__ h16 Bs[128 * 32];

    const int t = threadIdx.x;
    const int wave = t >> 6, lane = t & 63;
    const int quad = lane >> 4, l16 = lane & 15;
    const int m0 = blockIdx.y * 128, n0 = blockIdx.x * 128;
    const int wm = (wave >> 1) * 64, wn = (wave & 1) * 64;

    const int proj = blockIdx.z >> 2, bz = blockIdx.z & 3;
    const h16 *A, *Bt; h16* C;
    if (proj == 0)      { A = xh + bz * EW;       Bt = Wts;          C = KQV + bz * EW; }
    else if (proj == 1) { A = xh + (4 + bz) * EW; Bt = Wts + EW;     C = KQV + (4 + bz) * EW; }
    else                { A = Wts + 2 * EW;       Bt = xh + (8 + bz) * EW; C = KQV + (8 + bz) * EW; }

    const int sr = t >> 2;
    const int sg = (t & 3) * 8;

    f4 acc[4][4] = {};

    for (int k0 = 0; k0 < 1024; k0 += 32) {
        __syncthreads();
        async_copy16(As + sr * 32 + sg,        A  + (long)(m0 + sr) * E_DIM + k0 + sg);
        async_copy16(As + (sr + 64) * 32 + sg, A  + (long)(m0 + sr + 64) * E_DIM + k0 + sg);
        async_copy16(Bs + sr * 32 + sg,        Bt + (long)(n0 + sr) * E_DIM + k0 + sg);
        async_copy16(Bs + (sr + 64) * 32 + sg, Bt + (long)(n0 + sr + 64) * E_DIM + k0 + sg);
        __syncthreads();

        h8 av[4], bv[4];
        #pragma unroll
        for (int i = 0; i < 4; ++i) {
            av[i] = *reinterpret_cast<const h8*>(As + (wm + i * 16 + l16) * 32 + quad * 8);
            bv[i] = *reinterpret_cast<const h8*>(Bs + (wn + i * 16 + l16) * 32 + quad * 8);
        }
        #pragma unroll
        for (int mt = 0; mt < 4; ++mt)
            #pragma unroll
            for (int nt = 0; nt < 4; ++nt)
                acc[mt][nt] = __builtin_amdgcn_mfma_f32_16x16x32_f16(av[mt], bv[nt], acc[mt][nt], 0, 0, 0);
    }

    #pragma unroll
    for (int mt = 0; mt < 4; ++mt)
        #pragma unroll
        for (int i = 0; i < 4; ++i) {
            int m = m0 + wm + mt * 16 + quad * 4 + i;
            #pragma unroll
            for (int nt = 0; nt < 4; ++nt)
                C[(long)m * W_DIM + n0 + wn + nt * 16 + l16] = (h16)acc[mt][nt][i];
        }
}

// ---------------------------------------------------------------------------
// Output GEMM, batch-fused: out = M[1024x1024] x Ao[4096x1024]^T (+bias).
// 64x128 tiles -> 512 blocks (2/CU). DMA staging, double-buffered,
// ONE barrier per K-iter (DMA drained by next iter's barrier => overlap).
// ---------------------------------------------------------------------------
__global__ __launch_bounds__(256) void gemm_out(
    const h16* __restrict__ A, const h16* __restrict__ Bt,
    float* __restrict__ C, const float* __restrict__ bias)
{
    __shared__ h16 As[2][64 * 32];
    __shared__ h16 Bs[2][128 * 32];

    const int t = threadIdx.x;
    const int wave = t >> 6, lane = t & 63;
    const int quad = lane >> 4, l16 = lane & 15;
    const int m0 = blockIdx.y * 64, n0 = blockIdx.x * 128;
    const int wm = (wave >> 1) * 32, wn = (wave & 1) * 64;

    f4 acc[2][4] = {};

    // As: 256 granules (1/thread); Bs: 512 granules (2/thread); lane*16 pattern
    const int ga_r = t >> 2, ga_c = (t & 3) * 8;

    {   // stage k-tile 0 into buf 0
        async_copy16(&As[0][t * 8], A + (long)(m0 + ga_r) * E_DIM + ga_c);
        #pragma unroll
        for (int j = 0; j < 2; ++j) {
            int g = j * 256 + t;
            async_copy16(&Bs[0][g * 8], Bt + (long)(n0 + (g >> 2)) * E_DIM + (g & 3) * 8);
        }
    }

    for (int it = 0; it < 32; ++it) {
        __syncthreads();   // drains DMA for buf it&1; prev compute done
        if (it + 1 < 32) {
            int nb = (it + 1) & 1, k0 = (it + 1) * 32;
            async_copy16(&As[nb][t * 8], A + (long)(m0 + ga_r) * E_DIM + k0 + ga_c);
            #pragma unroll
            for (int j = 0; j < 2; ++j) {
                int g = j * 256 + t;
                async_copy16(&Bs[nb][g * 8], Bt + (long)(n0 + (g >> 2)) * E_DIM + k0 + (g & 3) * 8);
            }
        }
        const h16* as = As[it & 1];
        const h16* bs = Bs[it & 1];
        h8 av[2], bv[4];
        #pragma unroll
        for (int mt = 0; mt < 2; ++mt)
            av[mt] = *reinterpret_cast<const h8*>(as + (wm + mt * 16 + l16) * 32 + quad * 8);
        #pragma unroll
        for (int nt = 0; nt < 4; ++nt)
            bv[nt] = *reinterpret_cast<const h8*>(bs + (wn + nt * 16 + l16) * 32 + quad * 8);
        #pragma unroll
        for (int mt = 0; mt < 2; ++mt)
            #pragma unroll
            for (int nt = 0; nt < 4; ++nt)
                acc[mt][nt] = __builtin_amdgcn_mfma_f32_16x16x32_f16(av[mt], bv[nt], acc[mt][nt], 0, 0, 0);
    }

    #pragma unroll
    for (int mt = 0; mt < 2; ++mt)
        #pragma unroll
        for (int i = 0; i < 4; ++i) {
            int m = m0 + wm + mt * 16 + quad * 4 + i;
            float bv_ = bias ? bias[m] : 0.f;
            #pragma unroll
            for (int nt = 0; nt < 4; ++nt) {
                int n = n0 + wn + nt * 16 + l16;   // n = b*1024 + w
                C[(long)(n >> 10) * EW + (long)m * W_DIM + (n & 1023)] = acc[mt][nt][i] + bv_;
            }
        }
}

// ---------------------------------------------------------------------------
// MFMA flash attention (softmax over q). LDS-pipe-lean version:
//  - K fragments in registers straight from global (no K LDS)
//  - Q/V double-buffered via global_load_lds, ONE barrier/iter
//  - l via ones-MFMA (no sum shuffles); only max keeps 16 shuffles/iter
//  - XOR-swizzled unpadded tiles: DMA-legal + 2-way-free banks
// ---------------------------------------------------------------------------
__global__ __launch_bounds__(256) void attn_mfma(
    const h16* __restrict__ Kt, const h16* __restrict__ Qt,
    const h16* __restrict__ V, h16* __restrict__ AoT)
{
    __shared__ h16 Qs[2][64 * 64];   // [q][d], swizzled granules
    __shared__ h16 Vs[2][64 * 64];   // [d][q], swizzled granules
    __shared__ h16 Ps[4][16 * 72];   // per-wave P tile [k16][q64], pitch 72

    const int t = threadIdx.x, wave = t >> 6, lane = t & 63;
    const int quad = lane >> 4, l16 = lane & 15;
    const int b = blockIdx.y >> 4, h = blockIdx.y & 15;
    const int kt = 15 - blockIdx.x;   // heavy blocks dispatch first
    const int k0 = kt * 64;
    const int kw = wave * 16;

    const h16* Ktb = Kt + (long)b * EW + h * 64;
    const h16* Qtb = Qt + (long)b * EW + h * 64;
    const h16* Vb  = V  + (long)b * EW + (long)(h * 64) * W_DIM;

    // K fragments: row k0+kw+l16, d = c*32 + quad*8 .. +8
    h8 av0 = *reinterpret_cast<const h8*>(Ktb + (long)(k0 + kw + l16) * E_DIM + quad * 8);
    h8 av1 = *reinterpret_cast<const h8*>(Ktb + (long)(k0 + kw + l16) * E_DIM + 32 + quad * 8);

    // per-lane constant swizzle for fragment reads: rows nt*16+l16 -> row&7 = l16&7
    const int swz0 = ((quad) ^ (l16 & 7)) * 8;        // c=0: colg = quad
    const int swz1 = ((4 + quad) ^ (l16 & 7)) * 8;    // c=1: colg = 4+quad

    float mrow[4], al[4];
    #pragma unroll
    for (int i = 0; i < 4; ++i) mrow[i] = -1e30f;
    f4 O[4] = {};
    f4 Lacc = {};
    h8 ones;
    #pragma unroll
    for (int j = 0; j < 8; ++j) ones[j] = (h16)1.0f;

    // stage tile 0
    #pragma unroll
    for (int j = 0; j < 2; ++j) {
        int g = j * 256 + t, row = g >> 3, cg = (g & 7) ^ (row & 7);
        async_copy16(&Qs[0][g * 8], Qtb + (long)row * E_DIM + cg * 8);
        async_copy16(&Vs[0][g * 8], Vb + (long)row * W_DIM + cg * 8);
    }

    for (int it = 0; it <= kt; ++it) {
        const int q0 = it * 64;
        __syncthreads();   // drains DMA for buf it&1; prev iter's readers done
        if (it < kt) {
            int nb = (it + 1) & 1, q1 = q0 + 64;
            #pragma unroll
            for (int j = 0; j < 2; ++j) {
                int g = j * 256 + t, row = g >> 3, cg = (g & 7) ^ (row & 7);
                async_copy16(&Qs[nb][g * 8], Qtb + (long)(q1 + row) * E_DIM + cg * 8);
                async_copy16(&Vs[nb][g * 8], Vb + (long)row * W_DIM + q1 + cg * 8);
            }
        }
        const h16* qs = Qs[it & 1];
        const h16* vs = Vs[it & 1];

        // S[k][q]: rows k = k0+kw+quad*4+i, cols q = q0+nt*16+l16
        f4 S[4] = {};
        #pragma unroll
        for (int nt = 0; nt < 4; ++nt) {
            int rb = (nt * 16 + l16) * 64;
            h8 b0 = *reinterpret_cast<const h8*>(qs + rb + swz0);
            h8 b1 = *reinterpret_cast<const h8*>(qs + rb + swz1);
            S[nt] = __builtin_amdgcn_mfma_f32_16x16x32_f16(av0, b0, S[nt], 0, 0, 0);
            S[nt] = __builtin_amdgcn_mfma_f32_16x16x32_f16(av1, b1, S[nt], 0, 0, 0);
        }

        if (it == kt) {   // diagonal: mask q > k
            #pragma unroll
            for (int nt = 0; nt < 4; ++nt)
                #pragma unroll
                for (int i = 0; i < 4; ++i)
                    if (q0 + nt * 16 + l16 > k0 + kw + quad * 4 + i) S[nt][i] = -1e30f;
        }

        // online max along q (cols: nt x l16); al = rescale factor
        #pragma unroll
        for (int i = 0; i < 4; ++i) {
            float mx = fmaxf(fmaxf(S[0][i], S[1][i]), fmaxf(S[2][i], S[3][i]));
            mx = fmaxf(mx, __shfl_xor(mx, 1));
            mx = fmaxf(mx, __shfl_xor(mx, 2));
            mx = fmaxf(mx, __shfl_xor(mx, 4));
            mx = fmaxf(mx, __shfl_xor(mx, 8));
            float nm = fmaxf(mrow[i], mx);
            al[i] = __expf(mrow[i] - nm);
            mrow[i] = nm;
        }
        #pragma unroll
        for (int nt = 0; nt < 4; ++nt)
            #pragma unroll
            for (int i = 0; i < 4; ++i)
                S[nt][i] = __expf(S[nt][i] - mrow[i]);
        #pragma unroll
        for (int i = 0; i < 4; ++i) {
            Lacc[i] *= al[i];
            #pragma unroll
            for (int dt = 0; dt < 4; ++dt) O[dt][i] *= al[i];
        }

        // P -> per-wave LDS (D-layout), read back A-layout
        #pragma unroll
        for (int nt = 0; nt < 4; ++nt)
            #pragma unroll
            for (int i = 0; i < 4; ++i)
                Ps[wave][(quad * 4 + i) * 72 + nt * 16 + l16] = (h16)S[nt][i];
        asm volatile("" ::: "memory");   // DS in-order per wave; keep read after write

        // O[k][d] += P @ V^T ; l[k] += P @ 1  (same C-layout rows as O)
        #pragma unroll
        for (int c = 0; c < 2; ++c) {
            h8 pa = *reinterpret_cast<const h8*>(&Ps[wave][l16 * 72 + c * 32 + quad * 8]);
            Lacc = __builtin_amdgcn_mfma_f32_16x16x32_f16(pa, ones, Lacc, 0, 0, 0);
            int sw = c ? swz1 : swz0;
            #pragma unroll
            for (int dt = 0; dt < 4; ++dt) {
                h8 vv = *reinterpret_cast<const h8*>(vs + (dt * 16 + l16) * 64 + sw);
                O[dt] = __builtin_amdgcn_mfma_f32_16x16x32_f16(pa, vv, O[dt], 0, 0, 0);
            }
        }
    }

    // epilogue: AoT[b][k][h*64+d] = O / l * (1/32)
    #pragma unroll
    for (int dt = 0; dt < 4; ++dt)
        #pragma unroll
        for (int i = 0; i < 4; ++i)
            AoT[(long)b * EW + (long)(k0 + kw + quad * 4 + i) * E_DIM + h * 64 + dt * 16 + l16] =
                (h16)(O[dt][i] / Lacc[i] * 0.03125f);
}

// ---------------------------------------------------------------------------
extern "C" void kernel_launch(void* const* d_in, const int* in_sizes, int n_in,
                              void* d_out, int out_size, void* d_ws, size_t ws_size,
                              hipStream_t stream)
{
    const float* x  = (const float*)d_in[0];  // [3][B][E][W]; x[0]->K, x[1]->Q, x[2]->V
    const float* LQ = (const float*)d_in[1];
    const float* LK = (const float*)d_in[2];
    const float* LV = (const float*)d_in[3];
    const float* Mw = (const float*)d_in[4];
    const float* bb = (const float*)d_in[5];
    float* out = (float*)d_out;
    h16* ws = (h16*)d_ws;

    h16* xh  = ws;                    // [12][W][E] transposed x
    h16* LKh = ws + 12 * EW;          // weights [LK|LQ|LV|M]
    h16* Mh  = ws + 15 * EW;
    h16* Kp  = ws + 16 * EW;          // [B][W][E] (K^T)
    h16* Qp  = ws + 20 * EW;          // [B][W][E] (Q^T)
    h16* Vp  = ws + 24 * EW;          // [B][E][W] (V)
    h16* Ao  = ws + 28 * EW;          // [B][W][E] (attn out^T) = [4096][1024]

    dim3 blk(256);
    prep<<<dim3(16, 16, 16), blk, 0, stream>>>(x, LK, LQ, LV, Mw, xh, LKh);
    gemm_proj3<<<dim3(8, 8, 12), blk, 0, stream>>>(xh, LKh, Kp);
    attn_mfma<<<dim3(16, 64), blk, 0, stream>>>(Kp, Qp, Vp, Ao);
    gemm_out<<<dim3(32, 16), blk, 0, stream>>>(Mh, Ao, out, bb);
}